// Round 9
// baseline (507.671 us; speedup 1.0000x reference)
//
#include <hip/hip_runtime.h>
#include <hip/hip_bf16.h>
#include <math.h>

#define BB      8
#define DD      384
#define FDIM    256
#define NPIX    4096
#define NHEAD   8
#define NCLOUD  4
#define HDIM    48
#define GSZ     1024
#define TT      (BB*NPIX)     // 32768 tokens
#define DHID    (4*DD)        // 1536
#define TD      1152          // qkv fused row stride

typedef __hip_bfloat16 bf16;
typedef __attribute__((ext_vector_type(8))) short bf16x8;
typedef __attribute__((ext_vector_type(4))) float f32x4;
typedef __attribute__((ext_vector_type(2))) unsigned int u32x2;

__device__ __forceinline__ float b2f(bf16 x){ return __bfloat162float(x); }
__device__ __forceinline__ bf16  f2b(float x){ return __float2bfloat16(x); }
__device__ __forceinline__ float lo2f(unsigned u){ union{unsigned i; float f;} c; c.i = u << 16; return c.f; }
__device__ __forceinline__ float hi2f(unsigned u){ union{unsigned i; float f;} c; c.i = u & 0xffff0000u; return c.f; }
__device__ __forceinline__ unsigned short f2bs(float x){ bf16 b = f2b(x); return *(unsigned short*)&b; }
__device__ __forceinline__ unsigned pack2(float a, float b){
    return (unsigned)f2bs(a) | ((unsigned)f2bs(b) << 16);
}

#if defined(__has_builtin)
#if __has_builtin(__builtin_amdgcn_global_load_lds)
#define USE_GLL 1
#endif
#endif
#ifndef USE_GLL
#define USE_GLL 0
#endif

typedef __attribute__((address_space(1))) void gas_t;
typedef __attribute__((address_space(3))) void las_t;
__device__ __forceinline__ void gload16(const void* g, void* l){
#if USE_GLL
    __builtin_amdgcn_global_load_lds((gas_t*)(void*)g, (las_t*)l, 16, 0, 0);
#else
    *(bf16x8*)l = *(const bf16x8*)g;
#endif
}

// ---------------- block reduction helper ----------------
__device__ __forceinline__ float block_sum(float v, float* sm, int nthreads){
    #pragma unroll
    for (int o = 32; o > 0; o >>= 1) v += __shfl_down(v, o, 64);
    int nw = nthreads >> 6;
    __syncthreads();
    if ((threadIdx.x & 63) == 0) sm[threadIdx.x >> 6] = v;
    __syncthreads();
    float s = sm[0];
    for (int i = 1; i < nw; i++) s += sm[i];
    return s;
}

// ---------------- fused prologue: weights->bf16, film GEMM, invp, bias, zero stats ----------------
#define WSEG 147456            // 384*384
#define WBIG 589824            // 1536*384
__global__ void prologue(const float* Wq, const float* Wk, const float* Wv, const float* Wo,
                         const float* W1, const float* W2, bf16* wb,
                         const float* film, const float* ada1_W, const float* ada1_b,
                         const float* ada2_W, const float* ada2_b, float* gb1, float* gb2,
                         const int* perm, int* invp,
                         const float* bq, const float* bk, const float* bv, float* bqkv,
                         float* gxsq, float* gxsq2){
    int blk = blockIdx.x, tid = threadIdx.x;
    if (blk < 6912){
        int i = blk*256 + tid;
        float v;
        if      (i <   WSEG) v = Wq[i];
        else if (i < 2*WSEG) v = Wk[i -   WSEG];
        else if (i < 3*WSEG) v = Wv[i - 2*WSEG];
        else if (i < 4*WSEG) v = Wo[i - 3*WSEG];
        else if (i < 4*WSEG + WBIG) v = W1[i - 4*WSEG];
        else v = W2[i - 4*WSEG - WBIG];
        wb[i] = f2b(v);
    } else if (blk < 6960){
        int idx = (blk-6912)*256 + tid;           // < 12288
        int which = idx / (BB*768);
        int r = idx % (BB*768);
        int bb = r / 768, j = r % 768;
        const float* W = which ? ada2_W : ada1_W;
        const float* bi = which ? ada2_b : ada1_b;
        const float* f = film + bb*FDIM;
        const float* w = W + (size_t)j*FDIM;
        float s = 0.f;
        for (int i = 0; i < FDIM; i++) s += f[i]*w[i];
        (which ? gb2 : gb1)[bb*768 + j] = s + bi[j];
    } else if (blk < 6976){
        int i = (blk-6960)*256 + tid;
        if (i < NPIX) invp[perm[i]] = i;
    } else if (blk < 6981){
        int i = (blk-6976)*256 + tid;
        if (i < 384) bqkv[i] = bq[i];
        else if (i < 768) bqkv[i] = bk[i-384];
        else if (i < 1152) bqkv[i] = bv[i-768];
    } else {
        int i = (blk-6981)*256 + tid;             // 12 blocks -> 3072
        if (i < BB*DD){ gxsq[i] = 0.f; gxsq2[i] = 0.f; }
    }
}

// ---------------- prep1: img fp32 -> imgT bf16 (token-major) + per-(b,d) sumsq ----------------
__global__ void prep1(const float* img, bf16* imgT, float* gxsq){
    __shared__ float tile[32][33];
    __shared__ float red[32][8];
    int b = blockIdx.z, p0 = blockIdx.x*32, d0 = blockIdx.y*32;
    int tx = threadIdx.x, ty = threadIdx.y;     // 32 x 8
    #pragma unroll
    for (int i = 0; i < 32; i += 8)
        tile[ty+i][tx] = img[((size_t)b*DD + d0+ty+i)*NPIX + p0+tx];   // tile[d_local][pix_local]
    __syncthreads();
    #pragma unroll
    for (int i = 0; i < 32; i += 8){
        int p = p0 + ty + i;
        imgT[((size_t)(b<<12) + p)*DD + d0+tx] = f2b(tile[tx][ty+i]);
    }
    float s = 0.f;
    #pragma unroll
    for (int k = 0; k < 4; k++){ float v = tile[tx][ty*4 + k]; s += v*v; }
    red[tx][ty] = s;
    __syncthreads();
    if (ty == 0){
        float t2 = 0.f;
        #pragma unroll
        for (int k = 0; k < 8; k++) t2 += red[tx][k];
        atomicAdd(&gxsq[b*DD + d0+tx], t2);
    }
}

// GRN+film coefficient precompute (replaces grn_nx + per-token gather math):
// nx = sqrt(gxsq)/ (mean_d sqrt(gxsq) + 1e-6)
// adaLN output r = v*ca + cb  with  ca = ((1+gg)*nx + 1)*(1+g1),  cb = gbv*(1+g1) + g2
__global__ void grn_coef(const float* gin, const float* gg, const float* gbv,
                         const float* gb, float* ca, float* cb){
    __shared__ float sm[6];
    int b = blockIdx.x; int d = threadIdx.x;
    float g = sqrtf(gin[b*DD + d]);
    float tot = block_sum(g, sm, 384);
    float nx = g / (tot/(float)DD + 1e-6f);
    float g1 = 1.f + gb[b*768 + d];
    float g2 = gb[b*768 + 384 + d];
    ca[b*DD + d] = ((1.f + gg[d])*nx + 1.f)*g1;
    cb[b*DD + d] = gbv[d]*g1 + g2;
}

// adaLN1: wave per token; r = v*ca + cb, write to SHUFFLED slot
__global__ __launch_bounds__(256) void adaln1_tok(const bf16* imgT, const float* ca, const float* cb,
                        const int* invp, bf16* xt){
    int t = blockIdx.x*4 + (threadIdx.x >> 6);
    int lane = threadIdx.x & 63;
    int b = t >> 12, p = t & 4095;
    int j = invp[p];
    const unsigned* src = (const unsigned*)(imgT + (size_t)t*DD);
    unsigned* dst = (unsigned*)(xt + ((size_t)(b<<12) + j)*DD);
    int d0 = lane*6;
    const float2* cap = (const float2*)(ca + b*DD + d0);
    const float2* cbp = (const float2*)(cb + b*DD + d0);
    #pragma unroll
    for (int i = 0; i < 3; i++){
        unsigned u = src[lane*3 + i];
        float2 a = cap[i], c = cbp[i];
        dst[lane*3 + i] = pack2(lo2f(u)*a.x + c.x, hi2f(u)*a.y + c.y);
    }
}

// adaLN2: wave per token, no shuffle
__global__ __launch_bounds__(256) void adaln2_tok(const bf16* wi, const float* ca, const float* cb,
                        bf16* xout){
    int t = blockIdx.x*4 + (threadIdx.x >> 6);
    int lane = threadIdx.x & 63;
    int b = t >> 12;
    const unsigned* src = (const unsigned*)(wi + (size_t)t*DD);
    unsigned* dst = (unsigned*)(xout + (size_t)t*DD);
    int d0 = lane*6;
    const float2* cap = (const float2*)(ca + b*DD + d0);
    const float2* cbp = (const float2*)(cb + b*DD + d0);
    #pragma unroll
    for (int i = 0; i < 3; i++){
        unsigned u = src[lane*3 + i];
        float2 a = cap[i], c = cbp[i];
        dst[lane*3 + i] = pack2(lo2f(u)*a.x + c.x, hi2f(u)*a.y + c.y);
    }
}

// ---------------- MFMA bf16 GEMM:  C = A[M,K] @ W[N,K]^T + bias ----------------
// EXACT round-5 configuration (conv1 stable at 75.4-76.4 us over 3 clean builds):
// 128x128 tile, BK=32, 4 waves 2x2, GLL staging, XCD y-band remap, conflict-free
// XOR swizzle (0 conflicts), TRIPLE-buffered LDS, counted vmcnt(4) + one raw
// s_barrier per k-step. GEMM K-LOOP IS FROZEN (verified baseline).
// Accumulators swapped (C^T frags): lane holds 4 consecutive N-cols of one row.
// EPI: 0 none, 1 silu, 2 wi-fuse (C = imgT + (acc+bias)*csc, rows scattered)
//      + EPI=2 also accumulates GRN2 column sumsq into gxsq2 (colsq fused).
template<int EPI>
__global__ __launch_bounds__(256) void gemm_mfma(const bf16* __restrict__ A,
                          const bf16* __restrict__ W,
                          const float* __restrict__ bias,
                          bf16* __restrict__ C,
                          int M, int N, int K, const int* __restrict__ rowmap,
                          const bf16* __restrict__ imgT, const float* __restrict__ csc,
                          float* __restrict__ gxsq2){
    __shared__ short lds_[24576];           // 3 buffers x (A 4096 + W 4096 shorts)
    int tid  = threadIdx.x;
    int lane = tid & 63, wid = tid >> 6;
    int quad = lane >> 4, l16 = lane & 15;
    int wm = (wid >> 1) * 64, wn = (wid & 1) * 64;

    int v = blockIdx.y * gridDim.x + blockIdx.x;
    int xcd = v & 7, ii = v >> 3;
    int by = xcd * 32 + ii / gridDim.x;
    int bx = ii % gridDim.x;
    int m0 = by * 128, n0 = bx * 128;

    // hoisted staging sources (seg pre-swizzled within the 64B line) + LDS slots
    const bf16* sp[4]; int lof[4];
    #pragma unroll
    for (int it = 0; it < 4; it++){
        int s = tid + it*256;
        int half = s >> 9;
        int r = (s >> 2) & 127;
        int seg = (s & 3) ^ ((s >> 3) & 3);
        sp[it] = (half ? W + (size_t)(n0 + r)*K : A + (size_t)(m0 + r)*K) + seg*8;
        lof[it] = s*8;
    }
    int xorv = (quad ^ ((l16 >> 1) & 3)) * 8;   // swizzled read chunk offset (shorts)

    int nk = K >> 5;
    // prologue: stage k=0 -> buf0, k=1 -> buf1
    #pragma unroll
    for (int it = 0; it < 4; it++) gload16(sp[it], lds_ + lof[it]);
    if (nk > 1){
        #pragma unroll
        for (int it = 0; it < 4; it++) gload16(sp[it] + 32, lds_ + 8192 + lof[it]);
    }

    f32x4 acc[4][4] = {};
    for (int k = 0; k < nk; k++){
        if (k < nk-1) asm volatile("s_waitcnt vmcnt(4)" ::: "memory");
        else          asm volatile("s_waitcnt vmcnt(0)" ::: "memory");
        __builtin_amdgcn_s_barrier();
        __builtin_amdgcn_sched_barrier(0);
        if (k + 2 < nk){
            int koff = (k+2) * 32;
            int boff = ((k+2) % 3) * 8192;
            #pragma unroll
            for (int it = 0; it < 4; it++) gload16(sp[it] + koff, lds_ + boff + lof[it]);
        }
        const short* base = lds_ + (k % 3) * 8192;
        const short* a_ = base + (wm + l16)*32 + xorv;
        const short* w_ = base + 4096 + (wn + l16)*32 + xorv;
        bf16x8 af[4], wf[4];
        #pragma unroll
        for (int t = 0; t < 4; t++){
            af[t] = *(const bf16x8*)(void*)(a_ + t*512);
            wf[t] = *(const bf16x8*)(void*)(w_ + t*512);
        }
        #pragma unroll
        for (int i = 0; i < 4; i++)
            #pragma unroll
            for (int j2 = 0; j2 < 4; j2++)
                acc[i][j2] = __builtin_amdgcn_mfma_f32_16x16x32_bf16(wf[j2], af[i], acc[i][j2], 0, 0, 0);
        // no trailing barrier: next iteration's vmcnt+barrier protects buffers
    }
    // colsq fusion (EPI=2): LDS reusable after all waves pass a barrier post-k-loop
    float* colred = (float*)lds_;
    if (EPI == 2){
        __syncthreads();
        if (tid < 128) colred[tid] = 0.f;
        __syncthreads();
    }
    float csq[4][4] = {};
    // epilogue: lane (l16, quad) of wave (wm, wn) owns rows m0+wm+i*16+l16,
    // cols n0+wn+j2*16+quad*4 + {0..3}  (reg r = column offset)
    int nbase = n0 + wn + quad*4;
    f32x4 bsv[4], csv[4];
    #pragma unroll
    for (int j2 = 0; j2 < 4; j2++) bsv[j2] = *(const f32x4*)(bias + nbase + j2*16);
    if (EPI == 2){
        #pragma unroll
        for (int j2 = 0; j2 < 4; j2++) csv[j2] = *(const f32x4*)(csc + nbase + j2*16);
    }
    #pragma unroll
    for (int i = 0; i < 4; i++){
        int row = m0 + wm + i*16 + l16;
        int grow = rowmap ? ((row & ~4095) | rowmap[row & 4095]) : row;
        bf16* cp = C + (size_t)grow*N + nbase;
        const bf16* ip = imgT + (size_t)grow*DD + nbase;   // only used when EPI==2
        #pragma unroll
        for (int j2 = 0; j2 < 4; j2++){
            float v0 = acc[i][j2][0] + bsv[j2][0];
            float v1 = acc[i][j2][1] + bsv[j2][1];
            float v2 = acc[i][j2][2] + bsv[j2][2];
            float v3 = acc[i][j2][3] + bsv[j2][3];
            if (EPI == 1){
                v0 = v0 / (1.f + __expf(-v0));
                v1 = v1 / (1.f + __expf(-v1));
                v2 = v2 / (1.f + __expf(-v2));
                v3 = v3 / (1.f + __expf(-v3));
            }
            if (EPI == 2){
                u32x2 iw = *(const u32x2*)(void*)(ip + j2*16);
                v0 = lo2f(iw.x) + v0*csv[j2][0];
                v1 = hi2f(iw.x) + v1*csv[j2][1];
                v2 = lo2f(iw.y) + v2*csv[j2][2];
                v3 = hi2f(iw.y) + v3*csv[j2][3];
                csq[j2][0] += v0*v0;
                csq[j2][1] += v1*v1;
                csq[j2][2] += v2*v2;
                csq[j2][3] += v3*v3;
            }
            u32x2 st;
            st.x = pack2(v0, v1);
            st.y = pack2(v2, v3);
            *(u32x2*)(void*)(cp + j2*16) = st;
        }
    }
    if (EPI == 2){
        #pragma unroll
        for (int j2 = 0; j2 < 4; j2++)
            #pragma unroll
            for (int r = 0; r < 4; r++)
                atomicAdd(&colred[wn + quad*4 + j2*16 + r], csq[j2][r]);
        __syncthreads();
        if (tid < 128){
            int b = m0 >> 12;
            atomicAdd(&gxsq2[b*DD + n0 + tid], colred[tid]);
        }
    }
}

// LN over D=384 + elu + 1 for q and k inside fused qkv buffer. One wave per row.
__global__ __launch_bounds__(256) void ln_elu_qk(bf16* qkv,
                        const float* gq, const float* bq2,
                        const float* gk, const float* bk2){
    int r = blockIdx.x*4 + (threadIdx.x >> 6);
    int lane = threadIdx.x & 63;
    int t = r >> 1, which = r & 1;
    unsigned* row32 = (unsigned*)(qkv + (size_t)t*TD + which*384);
    const float* g = which ? gk : gq;
    const float* b = which ? bk2 : bq2;
    unsigned u[3];
    #pragma unroll
    for (int i = 0; i < 3; i++) u[i] = row32[lane*3 + i];
    float vv[6];
    #pragma unroll
    for (int i = 0; i < 3; i++){ vv[2*i] = lo2f(u[i]); vv[2*i+1] = hi2f(u[i]); }
    float s = 0.f;
    #pragma unroll
    for (int i = 0; i < 6; i++) s += vv[i];
    #pragma unroll
    for (int o = 32; o > 0; o >>= 1) s += __shfl_xor(s, o, 64);
    float mean = s / (float)DD;
    float s2 = 0.f;
    #pragma unroll
    for (int i = 0; i < 6; i++){ float d = vv[i]-mean; s2 += d*d; }
    #pragma unroll
    for (int o = 32; o > 0; o >>= 1) s2 += __shfl_xor(s2, o, 64);
    float rstd = rsqrtf(s2/(float)DD + 1e-5f);
    int d0 = lane*6;
    #pragma unroll
    for (int i = 0; i < 3; i++){
        float y0 = (vv[2*i]-mean)*rstd*g[d0+2*i] + b[d0+2*i];
        float y1 = (vv[2*i+1]-mean)*rstd*g[d0+2*i+1] + b[d0+2*i+1];
        y0 = (y0 > 0.f) ? y0 : expm1f(y0);
        y1 = (y1 > 0.f) ? y1 : expm1f(y1);
        row32[lane*3 + i] = pack2(y0 + 1.f, y1 + 1.f);
    }
}

// ---------------- kv + ksum via MFMA ----------------
// One block per (bc,h). C[d=48][e=64] = sum_n k[n,d]*v[n,e]; V column 48 = ones
// so ksum[d] lands in output column 48 (same trick as attn_apply's den column).
// Stage 256 tokens/iter into LDS TRANSPOSED (kT[d][n], vT[e][n], row stride 72
// shorts). Wave w consumes chunk w (64 tokens) -> 2 k-steps of 32 -> 12 MFMA.
// Cross-wave LDS tree-reduce, write kvbuf/ksumbuf directly.
__global__ __launch_bounds__(256) void kv_mfma(const bf16* __restrict__ qkv,
                                               float* __restrict__ kv,
                                               float* __restrict__ ksum){
    __shared__ __align__(16) short lds_[32256];   // staging 64.5KB; reduce reuses 48KB as float
    float* red = (float*)lds_;
    constexpr int KCH = 48*72;       // 3456 shorts per kT chunk
    constexpr int VCH = 64*72;       // 4608 shorts per vT chunk
    constexpr int VBASE = 4*KCH;     // 13824
    int tid = threadIdx.x;
    int lane = tid & 63, w = tid >> 6;
    int l16 = lane & 15, quad = lane >> 4;
    int bch = blockIdx.x;
    int bc = bch >> 3, h = bch & 7;

    f32x4 acc[3][4] = {};
    for (int it = 0; it < 4; it++){
        // load this thread's token (48 k + 48 v) into regs
        int nl = tid & 63;
        const bf16* tp = qkv + (size_t)(bc*GSZ + it*256 + tid)*TD + h*HDIM;
        bf16x8 kf[6], vf[6];
        #pragma unroll
        for (int c = 0; c < 6; c++){
            kf[c] = *(const bf16x8*)(void*)(tp + 384 + c*8);
            vf[c] = *(const bf16x8*)(void*)(tp + 768 + c*8);
        }
        __syncthreads();             // previous MFMA phase done before overwrite
        short* kt = lds_ + w*KCH;
        short* vt = lds_ + VBASE + w*VCH;
        #pragma unroll
        for (int c = 0; c < 6; c++)
            #pragma unroll
            for (int j = 0; j < 8; j++){
                kt[(c*8+j)*72 + nl] = kf[c][j];
                vt[(c*8+j)*72 + nl] = vf[c][j];
            }
        vt[48*72 + nl] = (short)0x3F80;   // ones row (bf16 1.0) -> ksum column
        __syncthreads();
        // MFMA: wave w consumes chunk w (rows 49..63 of vT unread garbage -> cols 49..63 only)
        const short* ka = lds_ + w*KCH;
        const short* va = lds_ + VBASE + w*VCH;
        #pragma unroll
        for (int ks = 0; ks < 2; ks++){
            int n0 = ks*32 + quad*8;
            bf16x8 af[3], bfr[4];
            #pragma unroll
            for (int i = 0; i < 3; i++)  af[i]  = *(const bf16x8*)(void*)(ka + (i*16+l16)*72 + n0);
            #pragma unroll
            for (int j2 = 0; j2 < 4; j2++) bfr[j2] = *(const bf16x8*)(void*)(va + (j2*16+l16)*72 + n0);
            #pragma unroll
            for (int i = 0; i < 3; i++)
                #pragma unroll
                for (int j2 = 0; j2 < 4; j2++)
                    acc[i][j2] = __builtin_amdgcn_mfma_f32_16x16x32_bf16(af[i], bfr[j2], acc[i][j2], 0, 0, 0);
        }
    }
    __syncthreads();
    // cross-wave reduce: C/D layout col=l16(+j2*16), row=quad*4+r(+i*16)
    #pragma unroll
    for (int i = 0; i < 3; i++)
        #pragma unroll
        for (int j2 = 0; j2 < 4; j2++)
            #pragma unroll
            for (int r = 0; r < 4; r++){
                int d = i*16 + quad*4 + r;
                int e = j2*16 + l16;
                red[w*3072 + d*64 + e] = acc[i][j2][r];
            }
    __syncthreads();
    for (int i = tid; i < 3072; i += 256){
        float s = red[i] + red[3072+i] + red[6144+i] + red[9216+i];
        int d = i >> 6, e = i & 63;
        if (e < 48)       kv[(size_t)bch*2304 + d*48 + e] = s;
        else if (e == 48) ksum[(size_t)bch*48 + d] = s;
    }
}

// attention apply (MFMA): per (bch, quarter) block, 256 rows, 4 waves x 64 rows.
// B matrix [K=64 x N=64] in LDS as W-layout Wm[col][k]: cols 0..47 = kv^T,
// col 48 = ksum (so den = extra output column), k 48..63 zero-padded.
// A fragments load 16B directly from the qkv q-rows (contiguous bf16).
__global__ __launch_bounds__(256) void attn_apply(const bf16* __restrict__ qkv,
                                                  const float* __restrict__ kv,
                                                  const float* __restrict__ ksum,
                                                  bf16* __restrict__ out){
    __shared__ __align__(16) bf16 Wm[64][72];   // +8 col pad: 144B row stride, 2-way banks max
    int bch = blockIdx.x >> 2, rs = blockIdx.x & 3;
    int bc = bch >> 3, h = bch & 7;
    int tid = threadIdx.x;
    int lane = tid & 63, w = tid >> 6;
    int l16 = lane & 15, quad = lane >> 4;

    // zero LDS (covers k-pad 48..63 and col-pad)
    for (int i = tid; i < 64*72; i += 256) ((unsigned short*)Wm)[i] = 0;
    __syncthreads();
    const float* kvh = kv + (size_t)bch*(HDIM*HDIM);
    for (int i = tid; i < HDIM*HDIM; i += 256){
        int e = i / HDIM, f = i - e*HDIM;
        Wm[f][e] = f2b(kvh[i]);                 // Wm[col=f][k=e] = kv[e][f]
    }
    if (tid < HDIM) Wm[HDIM][tid] = f2b(ksum[(size_t)bch*HDIM + tid]);  // den column
    __syncthreads();

    // B fragments: load once, keep in registers (reused for all 16 row-frags)
    bf16x8 bw[4][2];
    #pragma unroll
    for (int n = 0; n < 4; n++){
        bw[n][0] = *(const bf16x8*)(void*)&Wm[n*16 + l16][quad*8];
        bw[n][1] = *(const bf16x8*)(void*)&Wm[n*16 + l16][32 + quad*8];
    }

    int rowbase0 = bc*GSZ + rs*256 + w*64;
    #pragma unroll
    for (int frag = 0; frag < 4; frag++){
        int arow = rowbase0 + frag*16 + l16;
        const bf16* qp = qkv + (size_t)arow*TD + h*HDIM;
        bf16x8 a0 = *(const bf16x8*)(void*)(qp + quad*8);        // k 0..31
        bf16x8 a1 = {};
        if (quad < 2) a1 = *(const bf16x8*)(void*)(qp + 32 + quad*8);  // k 32..47; 48..63 zero
        f32x4 acc[4] = {};
        #pragma unroll
        for (int n = 0; n < 4; n++){
            acc[n] = __builtin_amdgcn_mfma_f32_16x16x32_bf16(a0, bw[n][0], acc[n], 0, 0, 0);
            acc[n] = __builtin_amdgcn_mfma_f32_16x16x32_bf16(a1, bw[n][1], acc[n], 0, 0, 0);
        }
        // den for rows quad*4+r lives in acc[3][r] of lane quad*16 (col 48)
        int orow0 = rowbase0 + frag*16 + quad*4;
        #pragma unroll
        for (int r = 0; r < 4; r++){
            float den = __shfl(acc[3][r], quad*16, 64);
            float inv = 1.f / (den + 1e-8f);
            bf16* op = out + (size_t)(orow0 + r)*DD + h*HDIM + l16;
            op[0]  = f2b(acc[0][r]*inv);
            op[16] = f2b(acc[1][r]*inv);
            op[32] = f2b(acc[2][r]*inv);
        }
    }
}

__global__ void final_out(const float* img, const bf16* wi, const bf16* fot,
                          const float* ffs, const float* fins, float* out){
    __shared__ float tile[32][33];
    int b = blockIdx.z, p0 = blockIdx.x*32, d0 = blockIdx.y*32;
    int tx = threadIdx.x, ty = threadIdx.y;
    #pragma unroll
    for (int i = 0; i < 32; i += 8){
        size_t t = (size_t)(b<<12) + p0+ty+i;
        tile[ty+i][tx] = b2f(wi[t*DD + d0+tx]) + b2f(fot[t*DD + d0+tx])*ffs[d0+tx];
    }
    __syncthreads();
    #pragma unroll
    for (int i = 0; i < 32; i += 8){
        int d = d0 + ty + i;
        size_t o = ((size_t)b*DD + d)*NPIX + p0+tx;
        out[o] = img[o] + tile[tx][ty+i]*fins[d];
    }
}

// ---------------- launch ----------------
extern "C" void kernel_launch(void* const* d_in, const int* in_sizes, int n_in,
                              void* d_out, int out_size, void* d_ws, size_t ws_size,
                              hipStream_t stream){
    const float* image   = (const float*)d_in[0];
    const float* film    = (const float*)d_in[1];
    const int*   perm    = (const int*)  d_in[2];
    const float* Wq      = (const float*)d_in[3];
    const float* bq      = (const float*)d_in[4];
    const float* Wk      = (const float*)d_in[5];
    const float* bk      = (const float*)d_in[6];
    const float* Wv      = (const float*)d_in[7];
    const float* bv      = (const float*)d_in[8];
    const float* Wo      = (const float*)d_in[9];
    const float* bo      = (const float*)d_in[10];
    const float* lnq_g   = (const float*)d_in[11];
    const float* lnq_b   = (const float*)d_in[12];
    const float* lnk_g   = (const float*)d_in[13];
    const float* lnk_b   = (const float*)d_in[14];
    const float* ada1_W  = (const float*)d_in[15];
    const float* ada1_b  = (const float*)d_in[16];
    const float* grn1_g  = (const float*)d_in[17];
    const float* grn1_b  = (const float*)d_in[18];
    const float* ada2_W  = (const float*)d_in[19];
    const float* ada2_b  = (const float*)d_in[20];
    const float* grn2_g  = (const float*)d_in[21];
    const float* grn2_b  = (const float*)d_in[22];
    const float* conv1_W = (const float*)d_in[23];
    const float* conv1_b = (const float*)d_in[24];
    const float* conv2_W = (const float*)d_in[25];
    const float* conv2_b = (const float*)d_in[26];
    const float* cs      = (const float*)d_in[27];
    const float* ffs     = (const float*)d_in[28];
    const float* fins    = (const float*)d_in[29];
    float* out = (float*)d_out;

    // ---- workspace ----
    char* m = (char*)d_ws;
    float* gb1     = (float*)m;  m += (size_t)BB*768*4;
    float* gb2     = (float*)m;  m += (size_t)BB*768*4;
    int*   invp    = (int*)m;    m += (size_t)NPIX*4;
    float* gxsq    = (float*)m;  m += (size_t)BB*DD*4;
    float* gxsq2   = (float*)m;  m += (size_t)BB*DD*4;
    float* cabuf   = (float*)m;  m += (size_t)BB*DD*4;
    float* cbbuf   = (float*)m;  m += (size_t)BB*DD*4;
    float* kvbuf   = (float*)m;  m += (size_t)256*HDIM*HDIM*4;
    float* ksumbuf = (float*)m;  m += (size_t)256*HDIM*4;
    float* bqkv    = (float*)m;  m += (size_t)TD*4;
    bf16*  wb      = (bf16*)m;   m += (size_t)(4*WSEG + 2*WBIG)*2;
    bf16*  wqkv = wb;
    bf16*  wbo  = wb + 3*WSEG;
    bf16*  wb1  = wb + 4*WSEG, *wb2 = wb + 4*WSEG + WBIG;
    bf16* imgT = (bf16*)m;       m += (size_t)TT*DD*2;            // 25.2 MB
    bf16* qkv = (bf16*)m;        m += (size_t)TT*TD*2;            // 75.5 MB
    bf16* obf = (bf16*)m;        m += (size_t)TT*DD*2;            // 25.2 MB (H1 overflow region)
    bf16* abf = (bf16*)m;        m += (size_t)TT*DD*2;            // 25.2 MB
    bf16* wi  = (bf16*)m;        m += (size_t)TT*DD*2;            // 25.2 MB
    bf16* H1  = qkv;             // 32768 x 1536 bf16 = qkv+obf exactly
    (void)obf;

    // ---- prologue (fused) ----
    prologue<<<6993, 256, 0, stream>>>(Wq, Wk, Wv, Wo, conv1_W, conv2_W, wb,
                                       film, ada1_W, ada1_b, ada2_W, ada2_b, gb1, gb2,
                                       perm, invp, bq, bk, bv, bqkv, gxsq, gxsq2);

    // ---- branch 1: cloud attention ----
    prep1<<<dim3(128,12,BB), dim3(32,8), 0, stream>>>(image, imgT, gxsq);
    grn_coef<<<BB, DD, 0, stream>>>(gxsq, grn1_g, grn1_b, gb1, cabuf, cbbuf);
    adaln1_tok<<<TT/4, 256, 0, stream>>>(imgT, cabuf, cbbuf, invp, abf);
    gemm_mfma<0><<<dim3(9,256), 256, 0, stream>>>(abf, wqkv, bqkv, qkv, TT, TD, DD, nullptr, nullptr, nullptr, nullptr);
    ln_elu_qk<<<2*TT/4, 256, 0, stream>>>(qkv, lnq_g, lnq_b, lnk_g, lnk_b);
    kv_mfma<<<256, 256, 0, stream>>>(qkv, kvbuf, ksumbuf);
    attn_apply<<<1024, 256, 0, stream>>>(qkv, kvbuf, ksumbuf, abf);          // attn-out -> abf
    // Wo GEMM fused with wi = imgT + ao*cs (scatter via perm) + GRN2 colsq accumulation
    gemm_mfma<2><<<dim3(3,256), 256, 0, stream>>>(abf, wbo, bo, wi, TT, DD, DD, perm, imgT, cs, gxsq2);

    // ---- branch 2: FFN ----
    grn_coef<<<BB, DD, 0, stream>>>(gxsq2, grn2_g, grn2_b, gb2, cabuf, cbbuf);
    adaln2_tok<<<TT/4, 256, 0, stream>>>(wi, cabuf, cbbuf, abf);             // x2 -> abf
    gemm_mfma<1><<<dim3(12,256), 256, 0, stream>>>(abf, wb1, conv1_b, H1, TT, DHID, DD, nullptr, nullptr, nullptr, nullptr);
    gemm_mfma<0><<<dim3(3,256), 256, 0, stream>>>(H1, wb2, conv2_b, abf, TT, DD, DHID, nullptr, nullptr, nullptr, nullptr); // fo -> abf
    final_out<<<dim3(128,12,BB), dim3(32,8), 0, stream>>>(image, wi, abf, ffs, fins, out);
}

// Round 10
// 497.737 us; speedup vs baseline: 1.0200x; 1.0200x over previous
//
#include <hip/hip_runtime.h>
#include <hip/hip_bf16.h>
#include <math.h>

#define BB      8
#define DD      384
#define FDIM    256
#define NPIX    4096
#define NHEAD   8
#define NCLOUD  4
#define HDIM    48
#define GSZ     1024
#define TT      (BB*NPIX)     // 32768 tokens
#define DHID    (4*DD)        // 1536
#define TD      1152          // qkv fused row stride

typedef __hip_bfloat16 bf16;
typedef __attribute__((ext_vector_type(8))) short bf16x8;
typedef __attribute__((ext_vector_type(4))) float f32x4;
typedef __attribute__((ext_vector_type(2))) unsigned int u32x2;

__device__ __forceinline__ float b2f(bf16 x){ return __bfloat162float(x); }
__device__ __forceinline__ bf16  f2b(float x){ return __float2bfloat16(x); }
__device__ __forceinline__ float lo2f(unsigned u){ union{unsigned i; float f;} c; c.i = u << 16; return c.f; }
__device__ __forceinline__ float hi2f(unsigned u){ union{unsigned i; float f;} c; c.i = u & 0xffff0000u; return c.f; }
__device__ __forceinline__ unsigned short f2bs(float x){ bf16 b = f2b(x); return *(unsigned short*)&b; }
__device__ __forceinline__ unsigned pack2(float a, float b){
    return (unsigned)f2bs(a) | ((unsigned)f2bs(b) << 16);
}

#if defined(__has_builtin)
#if __has_builtin(__builtin_amdgcn_global_load_lds)
#define USE_GLL 1
#endif
#endif
#ifndef USE_GLL
#define USE_GLL 0
#endif

typedef __attribute__((address_space(1))) void gas_t;
typedef __attribute__((address_space(3))) void las_t;
__device__ __forceinline__ void gload16(const void* g, void* l){
#if USE_GLL
    __builtin_amdgcn_global_load_lds((gas_t*)(void*)g, (las_t*)l, 16, 0, 0);
#else
    *(bf16x8*)l = *(const bf16x8*)g;
#endif
}

// ---------------- block reduction helper ----------------
__device__ __forceinline__ float block_sum(float v, float* sm, int nthreads){
    #pragma unroll
    for (int o = 32; o > 0; o >>= 1) v += __shfl_down(v, o, 64);
    int nw = nthreads >> 6;
    __syncthreads();
    if ((threadIdx.x & 63) == 0) sm[threadIdx.x >> 6] = v;
    __syncthreads();
    float s = sm[0];
    for (int i = 1; i < nw; i++) s += sm[i];
    return s;
}

// ---------------- fused prologue: weights->bf16, film GEMM, invp, bias, zero stats ----------------
#define WSEG 147456            // 384*384
#define WBIG 589824            // 1536*384
__global__ void prologue(const float* Wq, const float* Wk, const float* Wv, const float* Wo,
                         const float* W1, const float* W2, bf16* wb,
                         const float* film, const float* ada1_W, const float* ada1_b,
                         const float* ada2_W, const float* ada2_b, float* gb1, float* gb2,
                         const int* perm, int* invp,
                         const float* bq, const float* bk, const float* bv, float* bqkv,
                         float* gxsq, float* gxsq2){
    int blk = blockIdx.x, tid = threadIdx.x;
    if (blk < 6912){
        int i = blk*256 + tid;
        float v;
        if      (i <   WSEG) v = Wq[i];
        else if (i < 2*WSEG) v = Wk[i -   WSEG];
        else if (i < 3*WSEG) v = Wv[i - 2*WSEG];
        else if (i < 4*WSEG) v = Wo[i - 3*WSEG];
        else if (i < 4*WSEG + WBIG) v = W1[i - 4*WSEG];
        else v = W2[i - 4*WSEG - WBIG];
        wb[i] = f2b(v);
    } else if (blk < 6960){
        int idx = (blk-6912)*256 + tid;           // < 12288
        int which = idx / (BB*768);
        int r = idx % (BB*768);
        int bb = r / 768, j = r % 768;
        const float* W = which ? ada2_W : ada1_W;
        const float* bi = which ? ada2_b : ada1_b;
        const float* f = film + bb*FDIM;
        const float* w = W + (size_t)j*FDIM;
        float s = 0.f;
        for (int i = 0; i < FDIM; i++) s += f[i]*w[i];
        (which ? gb2 : gb1)[bb*768 + j] = s + bi[j];
    } else if (blk < 6976){
        int i = (blk-6960)*256 + tid;
        if (i < NPIX) invp[perm[i]] = i;
    } else if (blk < 6981){
        int i = (blk-6976)*256 + tid;
        if (i < 384) bqkv[i] = bq[i];
        else if (i < 768) bqkv[i] = bk[i-384];
        else if (i < 1152) bqkv[i] = bv[i-768];
    } else {
        int i = (blk-6981)*256 + tid;             // 12 blocks -> 3072
        if (i < BB*DD){ gxsq[i] = 0.f; gxsq2[i] = 0.f; }
    }
}

// ---------------- prep1: img fp32 -> imgT bf16 (token-major) + per-(b,d) sumsq ----------------
__global__ void prep1(const float* img, bf16* imgT, float* gxsq){
    __shared__ float tile[32][33];
    __shared__ float red[32][8];
    int b = blockIdx.z, p0 = blockIdx.x*32, d0 = blockIdx.y*32;
    int tx = threadIdx.x, ty = threadIdx.y;     // 32 x 8
    #pragma unroll
    for (int i = 0; i < 32; i += 8)
        tile[ty+i][tx] = img[((size_t)b*DD + d0+ty+i)*NPIX + p0+tx];   // tile[d_local][pix_local]
    __syncthreads();
    #pragma unroll
    for (int i = 0; i < 32; i += 8){
        int p = p0 + ty + i;
        imgT[((size_t)(b<<12) + p)*DD + d0+tx] = f2b(tile[tx][ty+i]);
    }
    float s = 0.f;
    #pragma unroll
    for (int k = 0; k < 4; k++){ float v = tile[tx][ty*4 + k]; s += v*v; }
    red[tx][ty] = s;
    __syncthreads();
    if (ty == 0){
        float t2 = 0.f;
        #pragma unroll
        for (int k = 0; k < 8; k++) t2 += red[tx][k];
        atomicAdd(&gxsq[b*DD + d0+tx], t2);
    }
}

// GRN+film coefficient precompute (replaces grn_nx + per-token gather math):
// nx = sqrt(gxsq)/ (mean_d sqrt(gxsq) + 1e-6)
// adaLN output r = v*ca + cb  with  ca = ((1+gg)*nx + 1)*(1+g1),  cb = gbv*(1+g1) + g2
__global__ void grn_coef(const float* gin, const float* gg, const float* gbv,
                         const float* gb, float* ca, float* cb){
    __shared__ float sm[6];
    int b = blockIdx.x; int d = threadIdx.x;
    float g = sqrtf(gin[b*DD + d]);
    float tot = block_sum(g, sm, 384);
    float nx = g / (tot/(float)DD + 1e-6f);
    float g1 = 1.f + gb[b*768 + d];
    float g2 = gb[b*768 + 384 + d];
    ca[b*DD + d] = ((1.f + gg[d])*nx + 1.f)*g1;
    cb[b*DD + d] = gbv[d]*g1 + g2;
}

// adaLN1: wave per token; r = v*ca + cb, write to SHUFFLED slot
__global__ __launch_bounds__(256) void adaln1_tok(const bf16* imgT, const float* ca, const float* cb,
                        const int* invp, bf16* xt){
    int t = blockIdx.x*4 + (threadIdx.x >> 6);
    int lane = threadIdx.x & 63;
    int b = t >> 12, p = t & 4095;
    int j = invp[p];
    const unsigned* src = (const unsigned*)(imgT + (size_t)t*DD);
    unsigned* dst = (unsigned*)(xt + ((size_t)(b<<12) + j)*DD);
    int d0 = lane*6;
    const float2* cap = (const float2*)(ca + b*DD + d0);
    const float2* cbp = (const float2*)(cb + b*DD + d0);
    #pragma unroll
    for (int i = 0; i < 3; i++){
        unsigned u = src[lane*3 + i];
        float2 a = cap[i], c = cbp[i];
        dst[lane*3 + i] = pack2(lo2f(u)*a.x + c.x, hi2f(u)*a.y + c.y);
    }
}

// adaLN2: wave per token, no shuffle
__global__ __launch_bounds__(256) void adaln2_tok(const bf16* wi, const float* ca, const float* cb,
                        bf16* xout){
    int t = blockIdx.x*4 + (threadIdx.x >> 6);
    int lane = threadIdx.x & 63;
    int b = t >> 12;
    const unsigned* src = (const unsigned*)(wi + (size_t)t*DD);
    unsigned* dst = (unsigned*)(xout + (size_t)t*DD);
    int d0 = lane*6;
    const float2* cap = (const float2*)(ca + b*DD + d0);
    const float2* cbp = (const float2*)(cb + b*DD + d0);
    #pragma unroll
    for (int i = 0; i < 3; i++){
        unsigned u = src[lane*3 + i];
        float2 a = cap[i], c = cbp[i];
        dst[lane*3 + i] = pack2(lo2f(u)*a.x + c.x, hi2f(u)*a.y + c.y);
    }
}

// ---------------- MFMA bf16 GEMM:  C = A[M,K] @ W[N,K]^T + bias ----------------
// EXACT round-8 template (signature AND body): conv1 stable 75.4-76.4 us across
// 3 clean builds with THIS signature. Round-9's signature change (extra gxsq2
// param + fused colsq code) regressed conv1 to 91 us with a byte-identical
// K-loop (rule: co-compiled template instantiations perturb codegen). DO NOT
// change this template's signature or add code to it.
// 128x128 tile, BK=32, 4 waves 2x2, GLL staging, XCD y-band remap, conflict-free
// XOR swizzle, triple-buffered LDS, counted vmcnt(4) + one raw s_barrier/k-step.
// Accumulators swapped (C^T frags): lane holds 4 consecutive N-cols of one row.
// EPI: 0 none, 1 silu, 2 wi-fuse (C = imgT + (acc+bias)*csc, rows scattered)
template<int EPI>
__global__ __launch_bounds__(256) void gemm_mfma(const bf16* __restrict__ A,
                          const bf16* __restrict__ W,
                          const float* __restrict__ bias,
                          bf16* __restrict__ C,
                          int M, int N, int K, const int* __restrict__ rowmap,
                          const bf16* __restrict__ imgT, const float* __restrict__ csc){
    __shared__ short lds_[24576];           // 3 buffers x (A 4096 + W 4096 shorts)
    int tid  = threadIdx.x;
    int lane = tid & 63, wid = tid >> 6;
    int quad = lane >> 4, l16 = lane & 15;
    int wm = (wid >> 1) * 64, wn = (wid & 1) * 64;

    int v = blockIdx.y * gridDim.x + blockIdx.x;
    int xcd = v & 7, ii = v >> 3;
    int by = xcd * 32 + ii / gridDim.x;
    int bx = ii % gridDim.x;
    int m0 = by * 128, n0 = bx * 128;

    // hoisted staging sources (seg pre-swizzled within the 64B line) + LDS slots
    const bf16* sp[4]; int lof[4];
    #pragma unroll
    for (int it = 0; it < 4; it++){
        int s = tid + it*256;
        int half = s >> 9;
        int r = (s >> 2) & 127;
        int seg = (s & 3) ^ ((s >> 3) & 3);
        sp[it] = (half ? W + (size_t)(n0 + r)*K : A + (size_t)(m0 + r)*K) + seg*8;
        lof[it] = s*8;
    }
    int xorv = (quad ^ ((l16 >> 1) & 3)) * 8;   // swizzled read chunk offset (shorts)

    int nk = K >> 5;
    // prologue: stage k=0 -> buf0, k=1 -> buf1
    #pragma unroll
    for (int it = 0; it < 4; it++) gload16(sp[it], lds_ + lof[it]);
    if (nk > 1){
        #pragma unroll
        for (int it = 0; it < 4; it++) gload16(sp[it] + 32, lds_ + 8192 + lof[it]);
    }

    f32x4 acc[4][4] = {};
    for (int k = 0; k < nk; k++){
        if (k < nk-1) asm volatile("s_waitcnt vmcnt(4)" ::: "memory");
        else          asm volatile("s_waitcnt vmcnt(0)" ::: "memory");
        __builtin_amdgcn_s_barrier();
        __builtin_amdgcn_sched_barrier(0);
        if (k + 2 < nk){
            int koff = (k+2) * 32;
            int boff = ((k+2) % 3) * 8192;
            #pragma unroll
            for (int it = 0; it < 4; it++) gload16(sp[it] + koff, lds_ + boff + lof[it]);
        }
        const short* base = lds_ + (k % 3) * 8192;
        const short* a_ = base + (wm + l16)*32 + xorv;
        const short* w_ = base + 4096 + (wn + l16)*32 + xorv;
        bf16x8 af[4], wf[4];
        #pragma unroll
        for (int t = 0; t < 4; t++){
            af[t] = *(const bf16x8*)(void*)(a_ + t*512);
            wf[t] = *(const bf16x8*)(void*)(w_ + t*512);
        }
        #pragma unroll
        for (int i = 0; i < 4; i++)
            #pragma unroll
            for (int j2 = 0; j2 < 4; j2++)
                acc[i][j2] = __builtin_amdgcn_mfma_f32_16x16x32_bf16(wf[j2], af[i], acc[i][j2], 0, 0, 0);
        // no trailing barrier: next iteration's vmcnt+barrier protects buffers
    }
    // epilogue: lane (l16, quad) of wave (wm, wn) owns rows m0+wm+i*16+l16,
    // cols n0+wn+j2*16+quad*4 + {0..3}  (reg r = column offset)
    int nbase = n0 + wn + quad*4;
    f32x4 bsv[4], csv[4];
    #pragma unroll
    for (int j2 = 0; j2 < 4; j2++) bsv[j2] = *(const f32x4*)(bias + nbase + j2*16);
    if (EPI == 2){
        #pragma unroll
        for (int j2 = 0; j2 < 4; j2++) csv[j2] = *(const f32x4*)(csc + nbase + j2*16);
    }
    #pragma unroll
    for (int i = 0; i < 4; i++){
        int row = m0 + wm + i*16 + l16;
        int grow = rowmap ? ((row & ~4095) | rowmap[row & 4095]) : row;
        bf16* cp = C + (size_t)grow*N + nbase;
        const bf16* ip = imgT + (size_t)grow*DD + nbase;   // only used when EPI==2
        #pragma unroll
        for (int j2 = 0; j2 < 4; j2++){
            float v0 = acc[i][j2][0] + bsv[j2][0];
            float v1 = acc[i][j2][1] + bsv[j2][1];
            float v2 = acc[i][j2][2] + bsv[j2][2];
            float v3 = acc[i][j2][3] + bsv[j2][3];
            if (EPI == 1){
                v0 = v0 / (1.f + __expf(-v0));
                v1 = v1 / (1.f + __expf(-v1));
                v2 = v2 / (1.f + __expf(-v2));
                v3 = v3 / (1.f + __expf(-v3));
            }
            if (EPI == 2){
                u32x2 iw = *(const u32x2*)(void*)(ip + j2*16);
                v0 = lo2f(iw.x) + v0*csv[j2][0];
                v1 = hi2f(iw.x) + v1*csv[j2][1];
                v2 = lo2f(iw.y) + v2*csv[j2][2];
                v3 = hi2f(iw.y) + v3*csv[j2][3];
            }
            u32x2 st;
            st.x = pack2(v0, v1);
            st.y = pack2(v2, v3);
            *(u32x2*)(void*)(cp + j2*16) = st;
        }
    }
}

// LN over D=384 + elu + 1 for q and k inside fused qkv buffer. One wave per row.
__global__ __launch_bounds__(256) void ln_elu_qk(bf16* qkv,
                        const float* gq, const float* bq2,
                        const float* gk, const float* bk2){
    int r = blockIdx.x*4 + (threadIdx.x >> 6);
    int lane = threadIdx.x & 63;
    int t = r >> 1, which = r & 1;
    unsigned* row32 = (unsigned*)(qkv + (size_t)t*TD + which*384);
    const float* g = which ? gk : gq;
    const float* b = which ? bk2 : bq2;
    unsigned u[3];
    #pragma unroll
    for (int i = 0; i < 3; i++) u[i] = row32[lane*3 + i];
    float vv[6];
    #pragma unroll
    for (int i = 0; i < 3; i++){ vv[2*i] = lo2f(u[i]); vv[2*i+1] = hi2f(u[i]); }
    float s = 0.f;
    #pragma unroll
    for (int i = 0; i < 6; i++) s += vv[i];
    #pragma unroll
    for (int o = 32; o > 0; o >>= 1) s += __shfl_xor(s, o, 64);
    float mean = s / (float)DD;
    float s2 = 0.f;
    #pragma unroll
    for (int i = 0; i < 6; i++){ float d = vv[i]-mean; s2 += d*d; }
    #pragma unroll
    for (int o = 32; o > 0; o >>= 1) s2 += __shfl_xor(s2, o, 64);
    float rstd = rsqrtf(s2/(float)DD + 1e-5f);
    int d0 = lane*6;
    #pragma unroll
    for (int i = 0; i < 3; i++){
        float y0 = (vv[2*i]-mean)*rstd*g[d0+2*i] + b[d0+2*i];
        float y1 = (vv[2*i+1]-mean)*rstd*g[d0+2*i+1] + b[d0+2*i+1];
        y0 = (y0 > 0.f) ? y0 : expm1f(y0);
        y1 = (y1 > 0.f) ? y1 : expm1f(y1);
        row32[lane*3 + i] = pack2(y0 + 1.f, y1 + 1.f);
    }
}

// ---------------- kv + ksum via MFMA ----------------
// One block per (bc,h). C[d=48][e=64] = sum_n k[n,d]*v[n,e]; V column 48 = ones
// so ksum[d] lands in output column 48 (same trick as attn_apply's den column).
// Stage 256 tokens/iter into LDS TRANSPOSED (kT[d][n], vT[e][n], row stride 72
// shorts). Wave w consumes chunk w (64 tokens) -> 2 k-steps of 32 -> 12 MFMA.
// Cross-wave LDS tree-reduce, write kvbuf/ksumbuf directly.
__global__ __launch_bounds__(256) void kv_mfma(const bf16* __restrict__ qkv,
                                               float* __restrict__ kv,
                                               float* __restrict__ ksum){
    __shared__ __align__(16) short lds_[32256];   // staging 64.5KB; reduce reuses 48KB as float
    float* red = (float*)lds_;
    constexpr int KCH = 48*72;       // 3456 shorts per kT chunk
    constexpr int VCH = 64*72;       // 4608 shorts per vT chunk
    constexpr int VBASE = 4*KCH;     // 13824
    int tid = threadIdx.x;
    int lane = tid & 63, w = tid >> 6;
    int l16 = lane & 15, quad = lane >> 4;
    int bch = blockIdx.x;
    int bc = bch >> 3, h = bch & 7;

    f32x4 acc[3][4] = {};
    for (int it = 0; it < 4; it++){
        // load this thread's token (48 k + 48 v) into regs
        int nl = tid & 63;
        const bf16* tp = qkv + (size_t)(bc*GSZ + it*256 + tid)*TD + h*HDIM;
        bf16x8 kf[6], vf[6];
        #pragma unroll
        for (int c = 0; c < 6; c++){
            kf[c] = *(const bf16x8*)(void*)(tp + 384 + c*8);
            vf[c] = *(const bf16x8*)(void*)(tp + 768 + c*8);
        }
        __syncthreads();             // previous MFMA phase done before overwrite
        short* kt = lds_ + w*KCH;
        short* vt = lds_ + VBASE + w*VCH;
        #pragma unroll
        for (int c = 0; c < 6; c++)
            #pragma unroll
            for (int j = 0; j < 8; j++){
                kt[(c*8+j)*72 + nl] = kf[c][j];
                vt[(c*8+j)*72 + nl] = vf[c][j];
            }
        vt[48*72 + nl] = (short)0x3F80;   // ones row (bf16 1.0) -> ksum column
        __syncthreads();
        // MFMA: wave w consumes chunk w (rows 49..63 of vT unread garbage -> cols 49..63 only)
        const short* ka = lds_ + w*KCH;
        const short* va = lds_ + VBASE + w*VCH;
        #pragma unroll
        for (int ks = 0; ks < 2; ks++){
            int n0 = ks*32 + quad*8;
            bf16x8 af[3], bfr[4];
            #pragma unroll
            for (int i = 0; i < 3; i++)  af[i]  = *(const bf16x8*)(void*)(ka + (i*16+l16)*72 + n0);
            #pragma unroll
            for (int j2 = 0; j2 < 4; j2++) bfr[j2] = *(const bf16x8*)(void*)(va + (j2*16+l16)*72 + n0);
            #pragma unroll
            for (int i = 0; i < 3; i++)
                #pragma unroll
                for (int j2 = 0; j2 < 4; j2++)
                    acc[i][j2] = __builtin_amdgcn_mfma_f32_16x16x32_bf16(af[i], bfr[j2], acc[i][j2], 0, 0, 0);
        }
    }
    __syncthreads();
    // cross-wave reduce: C/D layout col=l16(+j2*16), row=quad*4+r(+i*16)
    #pragma unroll
    for (int i = 0; i < 3; i++)
        #pragma unroll
        for (int j2 = 0; j2 < 4; j2++)
            #pragma unroll
            for (int r = 0; r < 4; r++){
                int d = i*16 + quad*4 + r;
                int e = j2*16 + l16;
                red[w*3072 + d*64 + e] = acc[i][j2][r];
            }
    __syncthreads();
    for (int i = tid; i < 3072; i += 256){
        float s = red[i] + red[3072+i] + red[6144+i] + red[9216+i];
        int d = i >> 6, e = i & 63;
        if (e < 48)       kv[(size_t)bch*2304 + d*48 + e] = s;
        else if (e == 48) ksum[(size_t)bch*48 + d] = s;
    }
}

// attention apply (MFMA): per (bch, quarter) block, 256 rows, 4 waves x 64 rows.
// B matrix [K=64 x N=64] in LDS as W-layout Wm[col][k]: cols 0..47 = kv^T,
// col 48 = ksum (so den = extra output column), k 48..63 zero-padded.
// A fragments load 16B directly from the qkv q-rows (contiguous bf16).
__global__ __launch_bounds__(256) void attn_apply(const bf16* __restrict__ qkv,
                                                  const float* __restrict__ kv,
                                                  const float* __restrict__ ksum,
                                                  bf16* __restrict__ out){
    __shared__ __align__(16) bf16 Wm[64][72];   // +8 col pad: 144B row stride, 2-way banks max
    int bch = blockIdx.x >> 2, rs = blockIdx.x & 3;
    int bc = bch >> 3, h = bch & 7;
    int tid = threadIdx.x;
    int lane = tid & 63, w = tid >> 6;
    int l16 = lane & 15, quad = lane >> 4;

    // zero LDS (covers k-pad 48..63 and col-pad)
    for (int i = tid; i < 64*72; i += 256) ((unsigned short*)Wm)[i] = 0;
    __syncthreads();
    const float* kvh = kv + (size_t)bch*(HDIM*HDIM);
    for (int i = tid; i < HDIM*HDIM; i += 256){
        int e = i / HDIM, f = i - e*HDIM;
        Wm[f][e] = f2b(kvh[i]);                 // Wm[col=f][k=e] = kv[e][f]
    }
    if (tid < HDIM) Wm[HDIM][tid] = f2b(ksum[(size_t)bch*HDIM + tid]);  // den column
    __syncthreads();

    // B fragments: load once, keep in registers (reused for all 16 row-frags)
    bf16x8 bw[4][2];
    #pragma unroll
    for (int n = 0; n < 4; n++){
        bw[n][0] = *(const bf16x8*)(void*)&Wm[n*16 + l16][quad*8];
        bw[n][1] = *(const bf16x8*)(void*)&Wm[n*16 + l16][32 + quad*8];
    }

    int rowbase0 = bc*GSZ + rs*256 + w*64;
    #pragma unroll
    for (int frag = 0; frag < 4; frag++){
        int arow = rowbase0 + frag*16 + l16;
        const bf16* qp = qkv + (size_t)arow*TD + h*HDIM;
        bf16x8 a0 = *(const bf16x8*)(void*)(qp + quad*8);        // k 0..31
        bf16x8 a1 = {};
        if (quad < 2) a1 = *(const bf16x8*)(void*)(qp + 32 + quad*8);  // k 32..47; 48..63 zero
        f32x4 acc[4] = {};
        #pragma unroll
        for (int n = 0; n < 4; n++){
            acc[n] = __builtin_amdgcn_mfma_f32_16x16x32_bf16(a0, bw[n][0], acc[n], 0, 0, 0);
            acc[n] = __builtin_amdgcn_mfma_f32_16x16x32_bf16(a1, bw[n][1], acc[n], 0, 0, 0);
        }
        // den for rows quad*4+r lives in acc[3][r] of lane quad*16 (col 48)
        int orow0 = rowbase0 + frag*16 + quad*4;
        #pragma unroll
        for (int r = 0; r < 4; r++){
            float den = __shfl(acc[3][r], quad*16, 64);
            float inv = 1.f / (den + 1e-8f);
            bf16* op = out + (size_t)(orow0 + r)*DD + h*HDIM + l16;
            op[0]  = f2b(acc[0][r]*inv);
            op[16] = f2b(acc[1][r]*inv);
            op[32] = f2b(acc[2][r]*inv);
        }
    }
}

// GRN2 column sumsq from wi (bf16, token-major); wave per 32-token chunk.
__global__ __launch_bounds__(256) void colsq(const bf16* wi, float* gxsq2){
    __shared__ float red[4][DD];
    int wave = threadIdx.x >> 6, lane = threadIdx.x & 63;
    int t0 = blockIdx.x*128 + wave*32;
    int b = (blockIdx.x*128) >> 12;
    int d0 = lane*6;
    float acc[6] = {};
    for (int it = 0; it < 32; it++){
        const unsigned* pw = (const unsigned*)(wi + (size_t)(t0 + it)*DD);
        #pragma unroll
        for (int i = 0; i < 3; i++){
            unsigned u = pw[lane*3 + i];
            float v0 = lo2f(u), v1 = hi2f(u);
            acc[2*i]   += v0*v0;
            acc[2*i+1] += v1*v1;
        }
    }
    #pragma unroll
    for (int i = 0; i < 6; i++) red[wave][d0+i] = acc[i];
    __syncthreads();
    for (int d = threadIdx.x; d < DD; d += 256){
        float s = red[0][d] + red[1][d] + red[2][d] + red[3][d];
        atomicAdd(&gxsq2[b*DD + d], s);
    }
}

__global__ void final_out(const float* img, const bf16* wi, const bf16* fot,
                          const float* ffs, const float* fins, float* out){
    __shared__ float tile[32][33];
    int b = blockIdx.z, p0 = blockIdx.x*32, d0 = blockIdx.y*32;
    int tx = threadIdx.x, ty = threadIdx.y;
    #pragma unroll
    for (int i = 0; i < 32; i += 8){
        size_t t = (size_t)(b<<12) + p0+ty+i;
        tile[ty+i][tx] = b2f(wi[t*DD + d0+tx]) + b2f(fot[t*DD + d0+tx])*ffs[d0+tx];
    }
    __syncthreads();
    #pragma unroll
    for (int i = 0; i < 32; i += 8){
        int d = d0 + ty + i;
        size_t o = ((size_t)b*DD + d)*NPIX + p0+tx;
        out[o] = img[o] + tile[tx][ty+i]*fins[d];
    }
}

// ---------------- launch ----------------
extern "C" void kernel_launch(void* const* d_in, const int* in_sizes, int n_in,
                              void* d_out, int out_size, void* d_ws, size_t ws_size,
                              hipStream_t stream){
    const float* image   = (const float*)d_in[0];
    const float* film    = (const float*)d_in[1];
    const int*   perm    = (const int*)  d_in[2];
    const float* Wq      = (const float*)d_in[3];
    const float* bq      = (const float*)d_in[4];
    const float* Wk      = (const float*)d_in[5];
    const float* bk      = (const float*)d_in[6];
    const float* Wv      = (const float*)d_in[7];
    const float* bv      = (const float*)d_in[8];
    const float* Wo      = (const float*)d_in[9];
    const float* bo      = (const float*)d_in[10];
    const float* lnq_g   = (const float*)d_in[11];
    const float* lnq_b   = (const float*)d_in[12];
    const float* lnk_g   = (const float*)d_in[13];
    const float* lnk_b   = (const float*)d_in[14];
    const float* ada1_W  = (const float*)d_in[15];
    const float* ada1_b  = (const float*)d_in[16];
    const float* grn1_g  = (const float*)d_in[17];
    const float* grn1_b  = (const float*)d_in[18];
    const float* ada2_W  = (const float*)d_in[19];
    const float* ada2_b  = (const float*)d_in[20];
    const float* grn2_g  = (const float*)d_in[21];
    const float* grn2_b  = (const float*)d_in[22];
    const float* conv1_W = (const float*)d_in[23];
    const float* conv1_b = (const float*)d_in[24];
    const float* conv2_W = (const float*)d_in[25];
    const float* conv2_b = (const float*)d_in[26];
    const float* cs      = (const float*)d_in[27];
    const float* ffs     = (const float*)d_in[28];
    const float* fins    = (const float*)d_in[29];
    float* out = (float*)d_out;

    // ---- workspace ----
    char* m = (char*)d_ws;
    float* gb1     = (float*)m;  m += (size_t)BB*768*4;
    float* gb2     = (float*)m;  m += (size_t)BB*768*4;
    int*   invp    = (int*)m;    m += (size_t)NPIX*4;
    float* gxsq    = (float*)m;  m += (size_t)BB*DD*4;
    float* gxsq2   = (float*)m;  m += (size_t)BB*DD*4;
    float* cabuf   = (float*)m;  m += (size_t)BB*DD*4;
    float* cbbuf   = (float*)m;  m += (size_t)BB*DD*4;
    float* kvbuf   = (float*)m;  m += (size_t)256*HDIM*HDIM*4;
    float* ksumbuf = (float*)m;  m += (size_t)256*HDIM*4;
    float* bqkv    = (float*)m;  m += (size_t)TD*4;
    bf16*  wb      = (bf16*)m;   m += (size_t)(4*WSEG + 2*WBIG)*2;
    bf16*  wqkv = wb;
    bf16*  wbo  = wb + 3*WSEG;
    bf16*  wb1  = wb + 4*WSEG, *wb2 = wb + 4*WSEG + WBIG;
    bf16* imgT = (bf16*)m;       m += (size_t)TT*DD*2;            // 25.2 MB
    bf16* qkv = (bf16*)m;        m += (size_t)TT*TD*2;            // 75.5 MB
    bf16* obf = (bf16*)m;        m += (size_t)TT*DD*2;            // 25.2 MB (H1 overflow region)
    bf16* abf = (bf16*)m;        m += (size_t)TT*DD*2;            // 25.2 MB
    bf16* wi  = (bf16*)m;        m += (size_t)TT*DD*2;            // 25.2 MB
    bf16* H1  = qkv;             // 32768 x 1536 bf16 = qkv+obf exactly
    (void)obf;

    // ---- prologue (fused) ----
    prologue<<<6993, 256, 0, stream>>>(Wq, Wk, Wv, Wo, conv1_W, conv2_W, wb,
                                       film, ada1_W, ada1_b, ada2_W, ada2_b, gb1, gb2,
                                       perm, invp, bq, bk, bv, bqkv, gxsq, gxsq2);

    // ---- branch 1: cloud attention ----
    prep1<<<dim3(128,12,BB), dim3(32,8), 0, stream>>>(image, imgT, gxsq);
    grn_coef<<<BB, DD, 0, stream>>>(gxsq, grn1_g, grn1_b, gb1, cabuf, cbbuf);
    adaln1_tok<<<TT/4, 256, 0, stream>>>(imgT, cabuf, cbbuf, invp, abf);
    gemm_mfma<0><<<dim3(9,256), 256, 0, stream>>>(abf, wqkv, bqkv, qkv, TT, TD, DD, nullptr, nullptr, nullptr);
    ln_elu_qk<<<2*TT/4, 256, 0, stream>>>(qkv, lnq_g, lnq_b, lnk_g, lnk_b);
    kv_mfma<<<256, 256, 0, stream>>>(qkv, kvbuf, ksumbuf);
    attn_apply<<<1024, 256, 0, stream>>>(qkv, kvbuf, ksumbuf, abf);          // attn-out -> abf
    // Wo GEMM fused with wi = imgT + ao*cs (scatter to natural order via perm)
    gemm_mfma<2><<<dim3(3,256), 256, 0, stream>>>(abf, wbo, bo, wi, TT, DD, DD, perm, imgT, cs);
    colsq<<<BB*32, 256, 0, stream>>>(wi, gxsq2);

    // ---- branch 2: FFN ----
    grn_coef<<<BB, DD, 0, stream>>>(gxsq2, grn2_g, grn2_b, gb2, cabuf, cbbuf);
    adaln2_tok<<<TT/4, 256, 0, stream>>>(wi, cabuf, cbbuf, abf);             // x2 -> abf
    gemm_mfma<1><<<dim3(12,256), 256, 0, stream>>>(abf, wb1, conv1_b, H1, TT, DHID, DD, nullptr, nullptr, nullptr);
    gemm_mfma<0><<<dim3(3,256), 256, 0, stream>>>(H1, wb2, conv2_b, abf, TT, DD, DHID, nullptr, nullptr, nullptr); // fo -> abf
    final_out<<<dim3(128,12,BB), dim3(32,8), 0, stream>>>(image, wi, abf, ffs, fins, out);
}